// Round 2
// baseline (13.019 us; speedup 1.0000x reference)
//
#include <hip/hip_runtime.h>

#define POOL 7
#define NCELL (POOL * POOL * POOL)   // 343
#define NUM_ROIS 64
#define DIMD 128
#define DIMH 128
#define DIMW 128
#define CH 32
#define CELLS_PER_BLK 32             // 32 cells * 8 channel-groups = 256 threads

__device__ __forceinline__ void axis_coords(int start, int size, int dim, int p,
                                            int& i0, int& i1, float& w) {
    float c = (float)start + ((float)p + 0.5f) * ((float)size / (float)POOL) - 0.5f;
    c = fminf(fmaxf(c, 0.0f), (float)(dim - 1));
    float f = floorf(c);
    i0 = (int)f;
    i1 = min(i0 + 1, dim - 1);
    w = c - f;
}

__global__ __launch_bounds__(256) void roi_align_3d(const float* __restrict__ img,
                                                    const int* __restrict__ rois,
                                                    float* __restrict__ out) {
    const int tid = threadIdx.x;
    const int cg = tid & 7;           // channel group: 4 floats each
    const int cell_in_blk = tid >> 3; // 0..31
    const int roi = blockIdx.y;
    const int cell = blockIdx.x * CELLS_PER_BLK + cell_in_blk;
    if (cell >= NCELL) return;

    const int px = cell / (POOL * POOL);
    const int rem = cell - px * (POOL * POOL);
    const int py = rem / POOL;
    const int pz = rem - py * POOL;

    const int* r = rois + roi * 6;
    const int sx = r[0], sy = r[1], sz = r[2];
    const int ex = r[3], ey = r[4], ez = r[5];

    int x0, x1, y0, y1, z0, z1;
    float wx, wy, wz;
    axis_coords(sx, ex, DIMD, px, x0, x1, wx);
    axis_coords(sy, ey, DIMH, py, y0, y1, wy);
    axis_coords(sz, ez, DIMW, pz, z0, z1, wz);

    const long sD = (long)DIMH * DIMW * CH;  // 524288
    const long sH = (long)DIMW * CH;         // 4096
    const long sW = CH;                      // 32

    const long bx0 = (long)x0 * sD, bx1 = (long)x1 * sD;
    const long by0 = (long)y0 * sH, by1 = (long)y1 * sH;
    const long bz0 = (long)z0 * sW + cg * 4, bz1 = (long)z1 * sW + cg * 4;

    const float4 v000 = *(const float4*)(img + bx0 + by0 + bz0);
    const float4 v001 = *(const float4*)(img + bx0 + by0 + bz1);
    const float4 v010 = *(const float4*)(img + bx0 + by1 + bz0);
    const float4 v011 = *(const float4*)(img + bx0 + by1 + bz1);
    const float4 v100 = *(const float4*)(img + bx1 + by0 + bz0);
    const float4 v101 = *(const float4*)(img + bx1 + by0 + bz1);
    const float4 v110 = *(const float4*)(img + bx1 + by1 + bz0);
    const float4 v111 = *(const float4*)(img + bx1 + by1 + bz1);

    const float ux = 1.0f - wx, uy = 1.0f - wy, uz = 1.0f - wz;
    const float w000 = ux * uy * uz;
    const float w100 = wx * uy * uz;
    const float w010 = ux * wy * uz;
    const float w110 = wx * wy * uz;
    const float w001 = ux * uy * wz;
    const float w101 = wx * uy * wz;
    const float w011 = ux * wy * wz;
    const float w111 = wx * wy * wz;

    float4 acc;
    acc.x = v000.x * w000 + v100.x * w100 + v010.x * w010 + v110.x * w110
          + v001.x * w001 + v101.x * w101 + v011.x * w011 + v111.x * w111;
    acc.y = v000.y * w000 + v100.y * w100 + v010.y * w010 + v110.y * w110
          + v001.y * w001 + v101.y * w101 + v011.y * w011 + v111.y * w111;
    acc.z = v000.z * w000 + v100.z * w100 + v010.z * w010 + v110.z * w110
          + v001.z * w001 + v101.z * w101 + v011.z * w011 + v111.z * w111;
    acc.w = v000.w * w000 + v100.w * w100 + v010.w * w010 + v110.w * w110
          + v001.w * w001 + v101.w * w101 + v011.w * w011 + v111.w * w111;

    *(float4*)(out + ((long)roi * NCELL + cell) * CH + cg * 4) = acc;
}

extern "C" void kernel_launch(void* const* d_in, const int* in_sizes, int n_in,
                              void* d_out, int out_size, void* d_ws, size_t ws_size,
                              hipStream_t stream) {
    const float* img = (const float*)d_in[0];
    const int* rois = (const int*)d_in[1];
    float* out = (float*)d_out;

    dim3 grid((NCELL + CELLS_PER_BLK - 1) / CELLS_PER_BLK, NUM_ROIS);
    roi_align_3d<<<grid, 256, 0, stream>>>(img, rois, out);
}

// Round 3
// 11.909 us; speedup vs baseline: 1.0932x; 1.0932x over previous
//
#include <hip/hip_runtime.h>

#define POOL 7
#define NCELL (POOL * POOL * POOL)   // 343
#define NUM_ROIS 64
#define DIMD 128
#define DIMH 128
#define DIMW 128
#define CH 32
#define CELLS_PER_BLK 32             // 32 cells * 8 channel-groups = 256 threads
#define CHUNKS ((NCELL + CELLS_PER_BLK - 1) / CELLS_PER_BLK)  // 11

__device__ __forceinline__ void axis_coords(int start, int size, int dim, int p,
                                            int& i0, int& i1, float& w) {
    float c = (float)start + ((float)p + 0.5f) * ((float)size / (float)POOL) - 0.5f;
    c = fminf(fmaxf(c, 0.0f), (float)(dim - 1));
    float f = floorf(c);
    i0 = (int)f;
    i1 = min(i0 + 1, dim - 1);
    w = c - f;
}

__global__ __launch_bounds__(256) void roi_align_3d(const float* __restrict__ img,
                                                    const int* __restrict__ rois,
                                                    float* __restrict__ out) {
    const int tid = threadIdx.x;
    const int cg = tid & 7;           // channel group: 4 floats each
    const int cell_in_blk = tid >> 3; // 0..31

    // XCD-locality swizzle: blk = chunk*64 + roi  =>  blk % 8 == roi % 8,
    // so all blocks of one ROI land on the same XCD (round-robin dispatch)
    // and shared corner lines dedup in that XCD's L2.
    const int blk = blockIdx.x;
    const int roi = blk & 63;
    const int chunk = blk >> 6;

    const int cell = chunk * CELLS_PER_BLK + cell_in_blk;
    if (cell >= NCELL) return;

    const int px = cell / (POOL * POOL);
    const int rem = cell - px * (POOL * POOL);
    const int py = rem / POOL;
    const int pz = rem - py * POOL;

    const int* r = rois + roi * 6;
    const int sx = r[0], sy = r[1], sz = r[2];
    const int ex = r[3], ey = r[4], ez = r[5];

    int x0, x1, y0, y1, z0, z1;
    float wx, wy, wz;
    axis_coords(sx, ex, DIMD, px, x0, x1, wx);
    axis_coords(sy, ey, DIMH, py, y0, y1, wy);
    axis_coords(sz, ez, DIMW, pz, z0, z1, wz);

    const long sD = (long)DIMH * DIMW * CH;  // 524288
    const long sH = (long)DIMW * CH;         // 4096
    const long sW = CH;                      // 32

    const long bx0 = (long)x0 * sD, bx1 = (long)x1 * sD;
    const long by0 = (long)y0 * sH, by1 = (long)y1 * sH;
    const long bz0 = (long)z0 * sW + cg * 4, bz1 = (long)z1 * sW + cg * 4;

    const float4 v000 = *(const float4*)(img + bx0 + by0 + bz0);
    const float4 v001 = *(const float4*)(img + bx0 + by0 + bz1);
    const float4 v010 = *(const float4*)(img + bx0 + by1 + bz0);
    const float4 v011 = *(const float4*)(img + bx0 + by1 + bz1);
    const float4 v100 = *(const float4*)(img + bx1 + by0 + bz0);
    const float4 v101 = *(const float4*)(img + bx1 + by0 + bz1);
    const float4 v110 = *(const float4*)(img + bx1 + by1 + bz0);
    const float4 v111 = *(const float4*)(img + bx1 + by1 + bz1);

    const float ux = 1.0f - wx, uy = 1.0f - wy, uz = 1.0f - wz;
    const float w000 = ux * uy * uz;
    const float w100 = wx * uy * uz;
    const float w010 = ux * wy * uz;
    const float w110 = wx * wy * uz;
    const float w001 = ux * uy * wz;
    const float w101 = wx * uy * wz;
    const float w011 = ux * wy * wz;
    const float w111 = wx * wy * wz;

    float4 acc;
    acc.x = v000.x * w000 + v100.x * w100 + v010.x * w010 + v110.x * w110
          + v001.x * w001 + v101.x * w101 + v011.x * w011 + v111.x * w111;
    acc.y = v000.y * w000 + v100.y * w100 + v010.y * w010 + v110.y * w110
          + v001.y * w001 + v101.y * w101 + v011.y * w011 + v111.y * w111;
    acc.z = v000.z * w000 + v100.z * w100 + v010.z * w010 + v110.z * w110
          + v001.z * w001 + v101.z * w101 + v011.z * w011 + v111.z * w111;
    acc.w = v000.w * w000 + v100.w * w100 + v010.w * w010 + v110.w * w110
          + v001.w * w001 + v101.w * w101 + v011.w * w011 + v111.w * w111;

    *(float4*)(out + ((long)roi * NCELL + cell) * CH + cg * 4) = acc;
}

extern "C" void kernel_launch(void* const* d_in, const int* in_sizes, int n_in,
                              void* d_out, int out_size, void* d_ws, size_t ws_size,
                              hipStream_t stream) {
    const float* img = (const float*)d_in[0];
    const int* rois = (const int*)d_in[1];
    float* out = (float*)d_out;

    roi_align_3d<<<dim3(NUM_ROIS * CHUNKS), 256, 0, stream>>>(img, rois, out);
}